// Round 14
// baseline (5261.218 us; speedup 1.0000x reference)
//
#include <hip/hip_runtime.h>
#include <math.h>
#include <stdint.h>

#define B 64
#define S 512
#define DIN 768
#define H 64
#define G4 256   // 4*H gates per direction
#define NG 512   // 2 directions * 4H
#define DM 128   // bidirectional output width

typedef _Float16 h2_t __attribute__((ext_vector_type(2)));
typedef _Float16 f16x8 __attribute__((ext_vector_type(8)));
typedef float f32x4 __attribute__((ext_vector_type(4)));

__device__ __forceinline__ h2_t u2h(uint32_t u) {
    h2_t h;
    __builtin_memcpy(&h, &u, 4);
    return h;
}

// Mixed-precision dot: f16 operands widened into v_fma_mix_f32 (FULL-rate
// VALU, ~2cy) instead of v_dot2_f32_f16 (quarter-rate, ~8cy -- R9's linear
// 2-chain scaling + low VALUBusy fingered the dot pipe as the step's issue
// bottleneck: 128 dots x 8cy ~= the whole 1233cy step).
__device__ __forceinline__ float dot2f(h2_t a, h2_t b, float acc) {
    acc = fmaf((float)a.x, (float)b.x, acc);
    return fmaf((float)a.y, (float)b.y, acc);
}

__device__ __forceinline__ float sigm(float x) {
    return 1.0f / (1.0f + __expf(-x));
}
__device__ __forceinline__ float tanh_fast(float x) {
    // tanh(x) = 1 - 2/(exp(2x)+1); exact at +-inf, ~1e-7 rel err
    return 1.0f - 2.0f / (__expf(2.0f * x) + 1.0f);
}

// ---------------------------------------------------------------------------
// Pooling: word_ids are sorted per row -> run-length accumulate, no atomics.
// FUSED MASK: word slot gets >=1 subword -> mask=1 at flush (mask pre-zeroed).
// ---------------------------------------------------------------------------
__global__ void pool_kernel(const float* __restrict__ emb,
                            const int* __restrict__ ids,
                            float* __restrict__ merged,
                            float* __restrict__ mask) {
    int b = blockIdx.x;
    int d = blockIdx.y * 128 + threadIdx.x;
    __shared__ int ids_s[S];
    for (int i = threadIdx.x; i < S; i += blockDim.x) ids_s[i] = ids[b * S + i];
    __syncthreads();
    const float* eb = emb + (size_t)b * S * DIN + d;
    float* mb = merged + (size_t)b * S * DIN + d;
    float acc = 0.f;
    for (int s = 0; s < S; ++s) {
        acc += eb[(size_t)s * DIN];
        int id = ids_s[s];
        bool flush = (s == S - 1) || (ids_s[s + 1] != id);
        if (flush) {
            mb[(size_t)id * DIN] = acc;
            acc = 0.f;
            if (blockIdx.y == 0 && threadIdx.x == 0)
                mask[b * S + id] = 1.0f;
        }
    }
}

// ---------------------------------------------------------------------------
// MFMA GEMM: C[m][n] = sum_k A[m][k]*Wt[n][k] + bias[n], via f16 MFMA.
// ---------------------------------------------------------------------------
#define LDK 40

__global__ __launch_bounds__(256, 2) void gemm_mfma(
    const float* __restrict__ A, int K,
    const float* __restrict__ Wt, const float* __restrict__ bias,
    float* __restrict__ C) {
    __shared__ __align__(16) _Float16 Alds[128][LDK];
    __shared__ __align__(16) _Float16 Blds[64][LDK];
    int tid = threadIdx.x;
    int lane = tid & 63;
    int wave = tid >> 6;
    int wm = wave >> 1, wn = wave & 1;
    int n0 = blockIdx.x * 64;
    int m0 = blockIdx.y * 128;

    int tr = tid >> 2;            // staging row 0..63
    int tc = (tid & 3) << 3;      // staging k-chunk (8 floats)

    f32x4 acc[4][2] = {};

    const float* Ab = A + (size_t)m0 * K;
    for (int k0 = 0; k0 < K; k0 += 32) {
        {
            const float* src = Ab + (size_t)tr * K + k0 + tc;
            float4 v0 = *(const float4*)(src);
            float4 v1 = *(const float4*)(src + 4);
            _Float16* dst = &Alds[tr][tc];
            dst[0] = (_Float16)v0.x; dst[1] = (_Float16)v0.y;
            dst[2] = (_Float16)v0.z; dst[3] = (_Float16)v0.w;
            dst[4] = (_Float16)v1.x; dst[5] = (_Float16)v1.y;
            dst[6] = (_Float16)v1.z; dst[7] = (_Float16)v1.w;
            src += (size_t)64 * K;
            float4 v2 = *(const float4*)(src);
            float4 v3 = *(const float4*)(src + 4);
            dst = &Alds[tr + 64][tc];
            dst[0] = (_Float16)v2.x; dst[1] = (_Float16)v2.y;
            dst[2] = (_Float16)v2.z; dst[3] = (_Float16)v2.w;
            dst[4] = (_Float16)v3.x; dst[5] = (_Float16)v3.y;
            dst[6] = (_Float16)v3.z; dst[7] = (_Float16)v3.w;
        }
        {
            const float* src = Wt + (size_t)(n0 + tr) * K + k0 + tc;
            float4 v0 = *(const float4*)(src);
            float4 v1 = *(const float4*)(src + 4);
            _Float16* dst = &Blds[tr][tc];
            dst[0] = (_Float16)v0.x; dst[1] = (_Float16)v0.y;
            dst[2] = (_Float16)v0.z; dst[3] = (_Float16)v0.w;
            dst[4] = (_Float16)v1.x; dst[5] = (_Float16)v1.y;
            dst[6] = (_Float16)v1.z; dst[7] = (_Float16)v1.w;
        }
        __syncthreads();

        int fr = lane & 15;
        int kg = (lane >> 4) << 3;
        f16x8 af[4], bf[2];
        #pragma unroll
        for (int mf = 0; mf < 4; ++mf)
            af[mf] = *(const f16x8*)&Alds[wm * 64 + mf * 16 + fr][kg];
        #pragma unroll
        for (int nf = 0; nf < 2; ++nf)
            bf[nf] = *(const f16x8*)&Blds[wn * 32 + nf * 16 + fr][kg];
        #pragma unroll
        for (int mf = 0; mf < 4; ++mf)
            #pragma unroll
            for (int nf = 0; nf < 2; ++nf)
                acc[mf][nf] = __builtin_amdgcn_mfma_f32_16x16x32_f16(
                    af[mf], bf[nf], acc[mf][nf], 0, 0, 0);
        __syncthreads();
    }

    int col = lane & 15;
    int r4 = (lane >> 4) << 2;
    #pragma unroll
    for (int nf = 0; nf < 2; ++nf) {
        int n = n0 + wn * 32 + nf * 16 + col;
        float bv = bias[n];
        #pragma unroll
        for (int mf = 0; mf < 4; ++mf) {
            #pragma unroll
            for (int reg = 0; reg < 4; ++reg) {
                int m = m0 + wm * 64 + mf * 16 + r4 + reg;
                C[(size_t)m * NG + n] = acc[mf][nf][reg] + bv;
            }
        }
    }
}

// ---------------------------------------------------------------------------
// Recurrence: ONE WAVE per (batch, direction). Zero barriers. EXACT R6/R7
// 263us structure: broadcast ds_reads at top, single accumulator per gate,
// scalar pre loads 4-deep, shh write + xout store + prefetch at bottom.
// ONLY change: dot2f now emits v_fma_mix_f32 (full-rate) instead of
// v_dot2_f32_f16 (quarter-rate).
// ---------------------------------------------------------------------------
__global__ __launch_bounds__(64, 1) void lstm_rec(
    const float* __restrict__ pre,   // [B*S][512]
    const float* __restrict__ Whh,   // [512][64] (dir*256+g rows)
    const float* __restrict__ xin,   // [B*S][128] or nullptr
    float* __restrict__ xout,        // [B*S][128]
    int residual) {
    int b = blockIdx.x >> 1;
    int dir = blockIdx.x & 1;
    int j = threadIdx.x & 63;

    h2_t wg0[32], wg1[32], wg2[32], wg3[32];
    {
        const float* w0 = Whh + (size_t)(dir * G4 + 0 * H + j) * H;
        const float* w1 = Whh + (size_t)(dir * G4 + 1 * H + j) * H;
        const float* w2 = Whh + (size_t)(dir * G4 + 2 * H + j) * H;
        const float* w3 = Whh + (size_t)(dir * G4 + 3 * H + j) * H;
        #pragma unroll
        for (int kk = 0; kk < 32; ++kk) {
            float2 v;
            h2_t p;
            v = *(const float2*)&w0[kk * 2];
            p.x = (_Float16)v.x; p.y = (_Float16)v.y; wg0[kk] = p;
            v = *(const float2*)&w1[kk * 2];
            p.x = (_Float16)v.x; p.y = (_Float16)v.y; wg1[kk] = p;
            v = *(const float2*)&w2[kk * 2];
            p.x = (_Float16)v.x; p.y = (_Float16)v.y; wg2[kk] = p;
            v = *(const float2*)&w3[kk * 2];
            p.x = (_Float16)v.x; p.y = (_Float16)v.y; wg3[kk] = p;
        }
    }

    const float* preb = pre + (size_t)b * S * NG + dir * G4 + j;
    const float* xinb = xin + (size_t)b * S * DM + dir * H + j;
    float* xoutb = xout + (size_t)b * S * DM + dir * H + j;

    float pi[4], pf[4], pg_[4], po[4], rb[4] = {0.f, 0.f, 0.f, 0.f};
    #pragma unroll
    for (int i = 0; i < 4; ++i) {
        int s = dir ? (S - 1 - i) : i;
        const float* p = preb + (size_t)s * NG;
        pi[i] = p[0];
        pf[i] = p[64];
        pg_[i] = p[128];
        po[i] = p[192];
        if (residual) rb[i] = xinb[(size_t)s * DM];
    }

    __shared__ __align__(16) _Float16 shh[64];
    shh[j] = (_Float16)0.f;

    float c = 0.f;
    #pragma unroll 4
    for (int step = 0; step < S; ++step) {
        int s = dir ? (S - 1 - step) : step;
        int q = step & 3;
        float rv = rb[q];

        // ---- broadcast-read all 64 h values (8 x ds_read_b128, uniform)
        uint4 hq[8];
        const uint4* hp = (const uint4*)shh;
        #pragma unroll
        for (int r = 0; r < 8; ++r) hq[r] = hp[r];

        // ---- dots (single accumulator per gate, 4 interleaved chains)
        float ai = pi[q], af = pf[q], ag = pg_[q], ao = po[q];
        #pragma unroll
        for (int r = 0; r < 8; ++r) {
            uint32_t uu[4] = {hq[r].x, hq[r].y, hq[r].z, hq[r].w};
            #pragma unroll
            for (int cc = 0; cc < 4; ++cc) {
                int kk = r * 4 + cc;
                h2_t hh = u2h(uu[cc]);
                ai = dot2f(hh, wg0[kk], ai);
                af = dot2f(hh, wg1[kk], af);
                ag = dot2f(hh, wg2[kk], ag);
                ao = dot2f(hh, wg3[kk], ao);
            }
        }

        // ---- activations
        c = sigm(af) * c + sigm(ai) * tanh_fast(ag);
        float h = sigm(ao) * tanh_fast(c);

        // ---- publish h (read at top of next step; same-wave DS ordering)
        shh[j] = (_Float16)h;

        // ---- store + prefetch tail
        int sn = step + 4;
        if (sn < S) {
            int s2 = dir ? (S - 1 - sn) : sn;
            const float* p = preb + (size_t)s2 * NG;
            pi[q] = p[0];
            pf[q] = p[64];
            pg_[q] = p[128];
            po[q] = p[192];
            if (residual) rb[q] = xinb[(size_t)s2 * DM];
        }
        xoutb[(size_t)s * DM] = h + rv;
    }
}

// ---------------------------------------------------------------------------
// Assemble: out0[b,s,0:128] = x, out0[b,s,128] = sn_word_len[b,s]
// ---------------------------------------------------------------------------
__global__ void assemble_kernel(const float* __restrict__ x,
                                const float* __restrict__ wl,
                                float* __restrict__ out0) {
    int idx = blockIdx.x * blockDim.x + threadIdx.x;
    if (idx >= B * S * 129) return;
    int c = idx % 129;
    int bs = idx / 129;
    out0[idx] = (c < 128) ? x[(size_t)bs * DM + c] : wl[bs];
}

extern "C" void kernel_launch(void* const* d_in, const int* in_sizes, int n_in,
                              void* d_out, int out_size, void* d_ws, size_t ws_size,
                              hipStream_t stream) {
    const float* emb  = (const float*)d_in[0];
    const float* wl   = (const float*)d_in[1];
    const float* Wih1 = (const float*)d_in[2];  // [512][768]
    const float* Whh1 = (const float*)d_in[3];  // [512][64]
    const float* b1   = (const float*)d_in[4];  // [512]
    const float* Wih  = (const float*)d_in[5];  // [7][512][128]
    const float* Whh  = (const float*)d_in[6];  // [7][512][64]
    const float* bb   = (const float*)d_in[7];  // [7][512]
    const int*   ids  = (const int*)d_in[8];

    float* out0 = (float*)d_out;
    float* mask_out = out0 + (size_t)B * S * 129;

    float* merged = (float*)d_ws;                       // 25165824 f
    float* pre    = merged + (size_t)B * S * DIN;       // 16777216 f
    float* xA     = pre + (size_t)B * S * NG;           //  4194304 f
    float* xB     = xA + (size_t)B * S * DM;            //  4194304 f

    hipMemsetAsync(merged, 0, (size_t)B * S * DIN * sizeof(float), stream);
    hipMemsetAsync(mask_out, 0, (size_t)B * S * sizeof(float), stream);
    pool_kernel<<<dim3(B, 6), 128, 0, stream>>>(emb, ids, merged, mask_out);

    dim3 ggrid(NG / 64, (B * S) / 128);   // (8, 256), N fastest

    // layer 1: 768 -> 128
    gemm_mfma<<<ggrid, 256, 0, stream>>>(merged, DIN, Wih1, b1, pre);
    lstm_rec<<<2 * B, 64, 0, stream>>>(pre, Whh1, nullptr, xA, 0);

    // layer 2: no residual
    gemm_mfma<<<ggrid, 256, 0, stream>>>(xA, DM, Wih, bb, pre);
    lstm_rec<<<2 * B, 64, 0, stream>>>(pre, Whh, nullptr, xB, 0);

    // layers 3..8: residual
    float* cur = xB;
    float* oth = xA;
    for (int l = 1; l < 7; ++l) {
        gemm_mfma<<<ggrid, 256, 0, stream>>>(cur, DM, Wih + (size_t)l * NG * DM,
                                             bb + (size_t)l * NG, pre);
        lstm_rec<<<2 * B, 64, 0, stream>>>(pre, Whh + (size_t)l * NG * H,
                                           cur, oth, 1);
        float* tmp = cur; cur = oth; oth = tmp;
    }
    // cur == xB after 6 swaps

    assemble_kernel<<<(B * S * 129 + 255) / 256, 256, 0, stream>>>(cur, wl, out0);
}

// Round 15
// 3352.393 us; speedup vs baseline: 1.5694x; 1.5694x over previous
//
#include <hip/hip_runtime.h>
#include <math.h>
#include <stdint.h>

#define B 64
#define S 512
#define DIN 768
#define H 64
#define G4 256   // 4*H gates per direction
#define NG 512   // 2 directions * 4H
#define DM 128   // bidirectional output width

typedef _Float16 h2_t __attribute__((ext_vector_type(2)));
typedef _Float16 f16x8 __attribute__((ext_vector_type(8)));
typedef float f32x4 __attribute__((ext_vector_type(4)));

#if defined(__has_builtin)
#if __has_builtin(__builtin_amdgcn_fdot2)
#define HAS_FDOT2 1
#endif
#endif

__device__ __forceinline__ h2_t u2h(uint32_t u) {
    h2_t h;
    __builtin_memcpy(&h, &u, 4);
    return h;
}

__device__ __forceinline__ float dot2f(h2_t a, h2_t b, float acc) {
#ifdef HAS_FDOT2
    return __builtin_amdgcn_fdot2(a, b, acc, false);
#else
    acc = fmaf((float)a.x, (float)b.x, acc);
    return fmaf((float)a.y, (float)b.y, acc);
#endif
}

__device__ __forceinline__ float sigm(float x) {
    return 1.0f / (1.0f + __expf(-x));
}
__device__ __forceinline__ float tanh_fast(float x) {
    return 1.0f - 2.0f / (__expf(2.0f * x) + 1.0f);
}

// ---------------------------------------------------------------------------
// Pooling: word_ids are sorted per row -> run-length accumulate, no atomics.
// FUSED MASK: word slot gets >=1 subword -> mask=1 at flush (mask pre-zeroed).
// ---------------------------------------------------------------------------
__global__ void pool_kernel(const float* __restrict__ emb,
                            const int* __restrict__ ids,
                            float* __restrict__ merged,
                            float* __restrict__ mask) {
    int b = blockIdx.x;
    int d = blockIdx.y * 128 + threadIdx.x;
    __shared__ int ids_s[S];
    for (int i = threadIdx.x; i < S; i += blockDim.x) ids_s[i] = ids[b * S + i];
    __syncthreads();
    const float* eb = emb + (size_t)b * S * DIN + d;
    float* mb = merged + (size_t)b * S * DIN + d;
    float acc = 0.f;
    for (int s = 0; s < S; ++s) {
        acc += eb[(size_t)s * DIN];
        int id = ids_s[s];
        bool flush = (s == S - 1) || (ids_s[s + 1] != id);
        if (flush) {
            mb[(size_t)id * DIN] = acc;
            acc = 0.f;
            if (blockIdx.y == 0 && threadIdx.x == 0)
                mask[b * S + id] = 1.0f;
        }
    }
}

// ---------------------------------------------------------------------------
// Layer-1 MFMA GEMM (K=768), BK=64: 12 K-iterations, 24 barriers (was 48).
// Coalesced float4 staging: consecutive tids load consecutive float4s.
// ---------------------------------------------------------------------------
#define LDK1 72

__global__ __launch_bounds__(256, 2) void gemm_mfma_k768(
    const float* __restrict__ A,
    const float* __restrict__ Wt, const float* __restrict__ bias,
    float* __restrict__ C) {
    __shared__ __align__(16) _Float16 Alds[128][LDK1];
    __shared__ __align__(16) _Float16 Blds[64][LDK1];
    int tid = threadIdx.x;
    int lane = tid & 63;
    int wave = tid >> 6;
    int wm = wave >> 1, wn = wave & 1;
    int n0 = blockIdx.x * 64;
    int m0 = blockIdx.y * 128;

    f32x4 acc[4][2] = {};

    for (int k0 = 0; k0 < DIN; k0 += 64) {
        // stage A tile 128x64 (8 x 256 float4, coalesced)
        #pragma unroll
        for (int it = 0; it < 8; ++it) {
            int idx = it * 256 + tid;
            int row = idx >> 4;
            int c4 = (idx & 15) << 2;
            float4 v = *(const float4*)&A[(size_t)(m0 + row) * DIN + k0 + c4];
            _Float16* d = &Alds[row][c4];
            d[0] = (_Float16)v.x; d[1] = (_Float16)v.y;
            d[2] = (_Float16)v.z; d[3] = (_Float16)v.w;
        }
        // stage B tile 64x64 (4 x 256 float4)
        #pragma unroll
        for (int it = 0; it < 4; ++it) {
            int idx = it * 256 + tid;
            int row = idx >> 4;
            int c4 = (idx & 15) << 2;
            float4 v = *(const float4*)&Wt[(size_t)(n0 + row) * DIN + k0 + c4];
            _Float16* d = &Blds[row][c4];
            d[0] = (_Float16)v.x; d[1] = (_Float16)v.y;
            d[2] = (_Float16)v.z; d[3] = (_Float16)v.w;
        }
        __syncthreads();

        int fr = lane & 15;
        int kg = (lane >> 4) << 3;
        #pragma unroll
        for (int kc = 0; kc < 2; ++kc) {
            f16x8 af[4], bf[2];
            #pragma unroll
            for (int mf = 0; mf < 4; ++mf)
                af[mf] = *(const f16x8*)&Alds[wm * 64 + mf * 16 + fr][kc * 32 + kg];
            #pragma unroll
            for (int nf = 0; nf < 2; ++nf)
                bf[nf] = *(const f16x8*)&Blds[wn * 32 + nf * 16 + fr][kc * 32 + kg];
            #pragma unroll
            for (int mf = 0; mf < 4; ++mf)
                #pragma unroll
                for (int nf = 0; nf < 2; ++nf)
                    acc[mf][nf] = __builtin_amdgcn_mfma_f32_16x16x32_f16(
                        af[mf], bf[nf], acc[mf][nf], 0, 0, 0);
        }
        __syncthreads();
    }

    int col = lane & 15;
    int r4 = (lane >> 4) << 2;
    #pragma unroll
    for (int nf = 0; nf < 2; ++nf) {
        int n = n0 + wn * 32 + nf * 16 + col;
        float bv = bias[n];
        #pragma unroll
        for (int mf = 0; mf < 4; ++mf) {
            #pragma unroll
            for (int reg = 0; reg < 4; ++reg) {
                int m = m0 + wm * 64 + mf * 16 + r4 + reg;
                C[(size_t)m * NG + n] = acc[mf][nf][reg] + bv;
            }
        }
    }
}

// ---------------------------------------------------------------------------
// K=128 MFMA GEMM (layers 2..8): SINGLE-SHOT — whole K staged in LDS
// (A 128x128 + B 64x128 f16 = 52KB, 2 blocks/CU), ONE barrier, 32 MFMAs.
// ---------------------------------------------------------------------------
#define LDK2 136

__global__ __launch_bounds__(256, 2) void gemm_mfma_k128(
    const float* __restrict__ A,
    const float* __restrict__ Wt, const float* __restrict__ bias,
    float* __restrict__ C) {
    __shared__ __align__(16) _Float16 Alds[128][LDK2];
    __shared__ __align__(16) _Float16 Blds[64][LDK2];
    int tid = threadIdx.x;
    int lane = tid & 63;
    int wave = tid >> 6;
    int wm = wave >> 1, wn = wave & 1;
    int n0 = blockIdx.x * 64;
    int m0 = blockIdx.y * 128;

    // stage A 128x128 (16 x 256 float4, coalesced)
    #pragma unroll
    for (int it = 0; it < 16; ++it) {
        int idx = it * 256 + tid;
        int row = idx >> 5;
        int c4 = (idx & 31) << 2;
        float4 v = *(const float4*)&A[(size_t)(m0 + row) * DM + c4];
        _Float16* d = &Alds[row][c4];
        d[0] = (_Float16)v.x; d[1] = (_Float16)v.y;
        d[2] = (_Float16)v.z; d[3] = (_Float16)v.w;
    }
    // stage B 64x128 (8 x 256 float4)
    #pragma unroll
    for (int it = 0; it < 8; ++it) {
        int idx = it * 256 + tid;
        int row = idx >> 5;
        int c4 = (idx & 31) << 2;
        float4 v = *(const float4*)&Wt[(size_t)(n0 + row) * DM + c4];
        _Float16* d = &Blds[row][c4];
        d[0] = (_Float16)v.x; d[1] = (_Float16)v.y;
        d[2] = (_Float16)v.z; d[3] = (_Float16)v.w;
    }
    __syncthreads();

    int fr = lane & 15;
    int kg = (lane >> 4) << 3;
    f32x4 acc[4][2] = {};
    #pragma unroll
    for (int kc = 0; kc < 4; ++kc) {
        f16x8 af[4], bf[2];
        #pragma unroll
        for (int mf = 0; mf < 4; ++mf)
            af[mf] = *(const f16x8*)&Alds[wm * 64 + mf * 16 + fr][kc * 32 + kg];
        #pragma unroll
        for (int nf = 0; nf < 2; ++nf)
            bf[nf] = *(const f16x8*)&Blds[wn * 32 + nf * 16 + fr][kc * 32 + kg];
        #pragma unroll
        for (int mf = 0; mf < 4; ++mf)
            #pragma unroll
            for (int nf = 0; nf < 2; ++nf)
                acc[mf][nf] = __builtin_amdgcn_mfma_f32_16x16x32_f16(
                    af[mf], bf[nf], acc[mf][nf], 0, 0, 0);
    }

    int col = lane & 15;
    int r4 = (lane >> 4) << 2;
    #pragma unroll
    for (int nf = 0; nf < 2; ++nf) {
        int n = n0 + wn * 32 + nf * 16 + col;
        float bv = bias[n];
        #pragma unroll
        for (int mf = 0; mf < 4; ++mf) {
            #pragma unroll
            for (int reg = 0; reg < 4; ++reg) {
                int m = m0 + wm * 64 + mf * 16 + r4 + reg;
                C[(size_t)m * NG + n] = acc[mf][nf][reg] + bv;
            }
        }
    }
}

// ---------------------------------------------------------------------------
// Recurrence: ONE WAVE per (batch, direction). Zero barriers. EXACT R6/R7
// 263us local optimum — 8 perturbations all regressed; do not touch.
// ---------------------------------------------------------------------------
__global__ __launch_bounds__(64, 1) void lstm_rec(
    const float* __restrict__ pre,   // [B*S][512]
    const float* __restrict__ Whh,   // [512][64] (dir*256+g rows)
    const float* __restrict__ xin,   // [B*S][128] or nullptr
    float* __restrict__ xout,        // [B*S][128]
    int residual) {
    int b = blockIdx.x >> 1;
    int dir = blockIdx.x & 1;
    int j = threadIdx.x & 63;

    h2_t wg0[32], wg1[32], wg2[32], wg3[32];
    {
        const float* w0 = Whh + (size_t)(dir * G4 + 0 * H + j) * H;
        const float* w1 = Whh + (size_t)(dir * G4 + 1 * H + j) * H;
        const float* w2 = Whh + (size_t)(dir * G4 + 2 * H + j) * H;
        const float* w3 = Whh + (size_t)(dir * G4 + 3 * H + j) * H;
        #pragma unroll
        for (int kk = 0; kk < 32; ++kk) {
            float2 v;
            h2_t p;
            v = *(const float2*)&w0[kk * 2];
            p.x = (_Float16)v.x; p.y = (_Float16)v.y; wg0[kk] = p;
            v = *(const float2*)&w1[kk * 2];
            p.x = (_Float16)v.x; p.y = (_Float16)v.y; wg1[kk] = p;
            v = *(const float2*)&w2[kk * 2];
            p.x = (_Float16)v.x; p.y = (_Float16)v.y; wg2[kk] = p;
            v = *(const float2*)&w3[kk * 2];
            p.x = (_Float16)v.x; p.y = (_Float16)v.y; wg3[kk] = p;
        }
    }

    const float* preb = pre + (size_t)b * S * NG + dir * G4 + j;
    const float* xinb = xin + (size_t)b * S * DM + dir * H + j;
    float* xoutb = xout + (size_t)b * S * DM + dir * H + j;

    float pi[4], pf[4], pg_[4], po[4], rb[4] = {0.f, 0.f, 0.f, 0.f};
    #pragma unroll
    for (int i = 0; i < 4; ++i) {
        int s = dir ? (S - 1 - i) : i;
        const float* p = preb + (size_t)s * NG;
        pi[i] = p[0];
        pf[i] = p[64];
        pg_[i] = p[128];
        po[i] = p[192];
        if (residual) rb[i] = xinb[(size_t)s * DM];
    }

    __shared__ __align__(16) _Float16 shh[64];
    shh[j] = (_Float16)0.f;

    float c = 0.f;
    #pragma unroll 4
    for (int step = 0; step < S; ++step) {
        int s = dir ? (S - 1 - step) : step;
        int q = step & 3;
        float rv = rb[q];

        uint4 hq[8];
        const uint4* hp = (const uint4*)shh;
        #pragma unroll
        for (int r = 0; r < 8; ++r) hq[r] = hp[r];

        float ai = pi[q], af = pf[q], ag = pg_[q], ao = po[q];
        #pragma unroll
        for (int r = 0; r < 8; ++r) {
            uint32_t uu[4] = {hq[r].x, hq[r].y, hq[r].z, hq[r].w};
            #pragma unroll
            for (int cc = 0; cc < 4; ++cc) {
                int kk = r * 4 + cc;
                h2_t hh = u2h(uu[cc]);
                ai = dot2f(hh, wg0[kk], ai);
                af = dot2f(hh, wg1[kk], af);
                ag = dot2f(hh, wg2[kk], ag);
                ao = dot2f(hh, wg3[kk], ao);
            }
        }

        c = sigm(af) * c + sigm(ai) * tanh_fast(ag);
        float h = sigm(ao) * tanh_fast(c);

        shh[j] = (_Float16)h;

        int sn = step + 4;
        if (sn < S) {
            int s2 = dir ? (S - 1 - sn) : sn;
            const float* p = preb + (size_t)s2 * NG;
            pi[q] = p[0];
            pf[q] = p[64];
            pg_[q] = p[128];
            po[q] = p[192];
            if (residual) rb[q] = xinb[(size_t)s2 * DM];
        }
        xoutb[(size_t)s * DM] = h + rv;
    }
}

// ---------------------------------------------------------------------------
// Assemble: out0[b,s,0:128] = x, out0[b,s,128] = sn_word_len[b,s]
// ---------------------------------------------------------------------------
__global__ void assemble_kernel(const float* __restrict__ x,
                                const float* __restrict__ wl,
                                float* __restrict__ out0) {
    int idx = blockIdx.x * blockDim.x + threadIdx.x;
    if (idx >= B * S * 129) return;
    int c = idx % 129;
    int bs = idx / 129;
    out0[idx] = (c < 128) ? x[(size_t)bs * DM + c] : wl[bs];
}

extern "C" void kernel_launch(void* const* d_in, const int* in_sizes, int n_in,
                              void* d_out, int out_size, void* d_ws, size_t ws_size,
                              hipStream_t stream) {
    const float* emb  = (const float*)d_in[0];
    const float* wl   = (const float*)d_in[1];
    const float* Wih1 = (const float*)d_in[2];  // [512][768]
    const float* Whh1 = (const float*)d_in[3];  // [512][64]
    const float* b1   = (const float*)d_in[4];  // [512]
    const float* Wih  = (const float*)d_in[5];  // [7][512][128]
    const float* Whh  = (const float*)d_in[6];  // [7][512][64]
    const float* bb   = (const float*)d_in[7];  // [7][512]
    const int*   ids  = (const int*)d_in[8];

    float* out0 = (float*)d_out;
    float* mask_out = out0 + (size_t)B * S * 129;

    float* merged = (float*)d_ws;                       // 25165824 f
    float* pre    = merged + (size_t)B * S * DIN;       // 16777216 f
    float* xA     = pre + (size_t)B * S * NG;           //  4194304 f
    float* xB     = xA + (size_t)B * S * DM;            //  4194304 f

    hipMemsetAsync(merged, 0, (size_t)B * S * DIN * sizeof(float), stream);
    hipMemsetAsync(mask_out, 0, (size_t)B * S * sizeof(float), stream);
    pool_kernel<<<dim3(B, 6), 128, 0, stream>>>(emb, ids, merged, mask_out);

    dim3 ggrid(NG / 64, (B * S) / 128);   // (8, 256), N fastest

    // layer 1: 768 -> 128
    gemm_mfma_k768<<<ggrid, 256, 0, stream>>>(merged, Wih1, b1, pre);
    lstm_rec<<<2 * B, 64, 0, stream>>>(pre, Whh1, nullptr, xA, 0);

    // layer 2: no residual
    gemm_mfma_k128<<<ggrid, 256, 0, stream>>>(xA, Wih, bb, pre);
    lstm_rec<<<2 * B, 64, 0, stream>>>(pre, Whh, nullptr, xB, 0);

    // layers 3..8: residual
    float* cur = xB;
    float* oth = xA;
    for (int l = 1; l < 7; ++l) {
        gemm_mfma_k128<<<ggrid, 256, 0, stream>>>(cur, Wih + (size_t)l * NG * DM,
                                                  bb + (size_t)l * NG, pre);
        lstm_rec<<<2 * B, 64, 0, stream>>>(pre, Whh + (size_t)l * NG * H,
                                           cur, oth, 1);
        float* tmp = cur; cur = oth; oth = tmp;
    }
    // cur == xB after 6 swaps

    assemble_kernel<<<(B * S * 129 + 255) / 256, 256, 0, stream>>>(cur, wl, out0);
}